// Round 2
// baseline (1189.386 us; speedup 1.0000x reference)
//
#include <hip/hip_runtime.h>

typedef __bf16 bf16_t;
typedef __bf16 bf16x8 __attribute__((ext_vector_type(8)));
typedef float floatx4 __attribute__((ext_vector_type(4)));

__device__ __forceinline__ float bf2f(bf16_t x) { return (float)x; }
__device__ __forceinline__ bf16_t f2bf(float x) { return (bf16_t)x; }

// ---------------------------------------------------------------------------
// fp32 -> bf16 elementwise convert (8 elems/thread, 16B stores). n8 = n/8.
// ---------------------------------------------------------------------------
__global__ __launch_bounds__(256) void cvt_f32_bf16(const float* __restrict__ in,
                                                    bf16_t* __restrict__ out,
                                                    int n8) {
    int i = blockIdx.x * blockDim.x + threadIdx.x;
    if (i >= n8) return;
    const float4* p = (const float4*)in + (size_t)i * 2;
    float4 a = p[0], b = p[1];
    bf16x8 v;
    v[0] = f2bf(a.x); v[1] = f2bf(a.y); v[2] = f2bf(a.z); v[3] = f2bf(a.w);
    v[4] = f2bf(b.x); v[5] = f2bf(b.y); v[6] = f2bf(b.z); v[7] = f2bf(b.w);
    *(bf16x8*)(out + (size_t)i * 8) = v;
}

// ---------------------------------------------------------------------------
// B^T GEMM: C[m][n] = sum_k A[m*K+k] * B[n*K+k].  B is bf16; A is fp32
// (converted during staging) or bf16; C is fp32 or bf16 (template).
// 128x128 tile, BK=32, 4 waves, 4x4 acc of mfma_f32_16x16x32_bf16.
// ---------------------------------------------------------------------------
template <typename AT, typename OT>
__global__ __launch_bounds__(256) void gemm_bt(const AT* __restrict__ A,
                                               const bf16_t* __restrict__ B,
                                               OT* __restrict__ C,
                                               int M, int N, int K) {
    __shared__ __attribute__((aligned(16))) bf16_t As[128 * 32];
    __shared__ __attribute__((aligned(16))) bf16_t Bs[128 * 32];
    const int tid = threadIdx.x;
    const int lane = tid & 63;
    const int w = tid >> 6;
    const int l15 = lane & 15, qd = lane >> 4;
    const int tm = blockIdx.y * 128, tn = blockIdx.x * 128;
    const int wm = (w >> 1) * 64, wn = (w & 1) * 64;

    floatx4 acc[4][4] = {};

    for (int k0 = 0; k0 < K; k0 += 32) {
#pragma unroll
        for (int it = 0; it < 2; ++it) {
            int c = tid + it * 256;          // 512 chunks of 8 elems
            int row = c >> 2, col = (c & 3) * 8;
            bf16x8 av;
            if constexpr (sizeof(AT) == 4) {
                const float* ap = (const float*)A + (size_t)(tm + row) * K + k0 + col;
                float4 lo = *(const float4*)ap;
                float4 hi = *(const float4*)(ap + 4);
                av[0] = f2bf(lo.x); av[1] = f2bf(lo.y);
                av[2] = f2bf(lo.z); av[3] = f2bf(lo.w);
                av[4] = f2bf(hi.x); av[5] = f2bf(hi.y);
                av[6] = f2bf(hi.z); av[7] = f2bf(hi.w);
            } else {
                av = *(const bf16x8*)((const bf16_t*)A + (size_t)(tm + row) * K + k0 + col);
            }
            *(bf16x8*)&As[row * 32 + col] = av;
            *(bf16x8*)&Bs[row * 32 + col] =
                *(const bf16x8*)&B[(size_t)(tn + row) * K + k0 + col];
        }
        __syncthreads();
        bf16x8 af[4], bfr[4];
#pragma unroll
        for (int i = 0; i < 4; i++)
            af[i] = *(const bf16x8*)&As[(wm + i * 16 + l15) * 32 + qd * 8];
#pragma unroll
        for (int j = 0; j < 4; j++)
            bfr[j] = *(const bf16x8*)&Bs[(wn + j * 16 + l15) * 32 + qd * 8];
#pragma unroll
        for (int i = 0; i < 4; i++)
#pragma unroll
            for (int j = 0; j < 4; j++)
                acc[i][j] = __builtin_amdgcn_mfma_f32_16x16x32_bf16(
                    af[i], bfr[j], acc[i][j], 0, 0, 0);
        __syncthreads();
    }
    // C/D layout: col = lane&15, row = quad*4 + reg  (m89/m91 verified)
#pragma unroll
    for (int i = 0; i < 4; i++) {
        int row = tm + wm + i * 16 + qd * 4;
#pragma unroll
        for (int j = 0; j < 4; j++) {
            int col = tn + wn + j * 16 + l15;
#pragma unroll
            for (int r = 0; r < 4; r++)
                C[(size_t)(row + r) * N + col] = (OT)acc[i][j][r];
        }
    }
}

// ---------------------------------------------------------------------------
// Reference-faithful "norm" + RoPE + layout transform.
// NOTE: reference does q = rsqrt(mean(q*q)+eps) * q_weight  (NO multiply by q!)
// qkv row-major (B*T, 5120) bf16; qw/kw fp32.  One wave per (row, head-slot).
// q -> (B,H,T,D), k -> (B,KV,T,D) (normed+roped), v -> (B,KV,T,D) copy.
// ---------------------------------------------------------------------------
__global__ __launch_bounds__(256) void rmsrope(const bf16_t* __restrict__ qkv,
                                               const float* __restrict__ qw,
                                               const float* __restrict__ kw,
                                               bf16_t* __restrict__ q_r,
                                               bf16_t* __restrict__ k_r,
                                               bf16_t* __restrict__ v_r) {
    const int tid = threadIdx.x, lane = tid & 63, w = tid >> 6;
    const int slot = blockIdx.x * 4 + w;       // [0, 163840)
    const int row = slot / 40;
    const int hs = slot - row * 40;
    const int b = row >> 11, t = row & 2047;
    const bf16_t* src = qkv + (size_t)row * 5120 + hs * 128;

    if (hs >= 36) {  // v: passthrough reshape
        size_t dst = ((size_t)((b * 4 + (hs - 36)) * 2048 + t)) * 128;
        v_r[dst + lane] = src[lane];
        v_r[dst + lane + 64] = src[lane + 64];
        return;
    }
    float x1 = bf2f(src[lane]);
    float x2 = bf2f(src[lane + 64]);
    float ss = x1 * x1 + x2 * x2;
#pragma unroll
    for (int off = 1; off < 64; off <<= 1) ss += __shfl_xor(ss, off);
    const float rr = rsqrtf(ss * (1.0f / 128.0f) + 1e-6f);

    const float* wp;
    bf16_t* dstp;
    if (hs < 32) {
        wp = qw + hs * 128;
        dstp = q_r + ((size_t)((b * 32 + hs) * 2048 + t)) * 128;
    } else {
        wp = kw + (hs - 32) * 128;
        dstp = k_r + ((size_t)((b * 4 + (hs - 32)) * 2048 + t)) * 128;
    }
    float n1 = rr * wp[lane];        // reference: rsqrt(...) * weight (no * x)
    float n2 = rr * wp[lane + 64];
    // inv_freq = 10000^(-lane/64) = exp2(-lane * log2(10000)/64)
    float inv_freq = exp2f((float)lane * -0.20762050593046f);
    float th = (float)t * inv_freq;
    float sn, cs;
    sincosf(th, &sn, &cs);
    dstp[lane] = f2bf(n1 * cs - n2 * sn);
    dstp[lane + 64] = f2bf(n1 * sn + n2 * cs);
}

// ---------------------------------------------------------------------------
// Flash attention (non-causal, full softmax over T=2048 keys).
// Block: 4 waves, Q-tile 128 (32 rows/wave), K-tile 64, D=128.
// ---------------------------------------------------------------------------
#define ATT_SCALE 0.08838834764831845f

__global__ __launch_bounds__(256, 1) void flash_attn(const bf16_t* __restrict__ Qr,
                                                     const bf16_t* __restrict__ Kr,
                                                     const bf16_t* __restrict__ Vr,
                                                     bf16_t* __restrict__ Oo) {
    __shared__ __attribute__((aligned(16))) bf16_t Qs[128 * 136];
    __shared__ __attribute__((aligned(16))) bf16_t Ks[64 * 136];
    __shared__ __attribute__((aligned(16))) bf16_t Vts[128 * 72];  // Vts[d][k]
    __shared__ __attribute__((aligned(16))) bf16_t Ps[4][32 * 72];
    const int tid = threadIdx.x, lane = tid & 63, w = tid >> 6;
    const int l15 = lane & 15, qd = lane >> 4;
    const int qt = blockIdx.x, bh = blockIdx.y;
    const int b = bh >> 5, h = bh & 31;
    const int kvh = h >> 3;  // GROUP = 8
    const bf16_t* Qb = Qr + ((size_t)(b * 32 + h) * 2048 + qt * 128) * 128;
    const bf16_t* Kb = Kr + ((size_t)(b * 4 + kvh) * 2048) * 128;
    const bf16_t* Vb = Vr + ((size_t)(b * 4 + kvh) * 2048) * 128;

    // Load Q tile (128 x 128) once.
#pragma unroll
    for (int it = 0; it < 8; ++it) {
        int c = it * 256 + tid;
        int row = c >> 4, col = (c & 15) * 8;
        *(bf16x8*)&Qs[row * 136 + col] = *(const bf16x8*)&Qb[row * 128 + col];
    }

    float m_s[2][4], l_s[2][4];
    floatx4 oacc[2][8] = {};
#pragma unroll
    for (int i = 0; i < 2; i++)
#pragma unroll
        for (int r = 0; r < 4; r++) { m_s[i][r] = -1e30f; l_s[i][r] = 0.0f; }

    const int wrow = w * 32;

    for (int kt = 0; kt < 32; ++kt) {
        __syncthreads();  // prev iteration's reads of Ks/Vts done (also Qs ready)
        // stage K tile (64 x 128) -> Ks
#pragma unroll
        for (int it = 0; it < 4; ++it) {
            int c = it * 256 + tid;
            int row = c >> 4, col = (c & 15) * 8;
            *(bf16x8*)&Ks[row * 136 + col] =
                *(const bf16x8*)&Kb[(size_t)(kt * 64 + row) * 128 + col];
        }
        // stage V tile transposed: Vts[d][k] = V[k][d] (lane = k, conflict-free)
#pragma unroll
        for (int it = 0; it < 4; ++it) {
            int d0 = (it * 4 + w) * 8;
            bf16x8 v = *(const bf16x8*)&Vb[(size_t)(kt * 64 + lane) * 128 + d0];
#pragma unroll
            for (int e = 0; e < 8; ++e) Vts[(d0 + e) * 72 + lane] = v[e];
        }
        __syncthreads();

        // S = Q K^T for this wave's 32 rows x 64 keys
        floatx4 sacc[2][4] = {};
#pragma unroll
        for (int kk = 0; kk < 128; kk += 32) {
            bf16x8 af[2], bfr[4];
#pragma unroll
            for (int i = 0; i < 2; i++)
                af[i] = *(const bf16x8*)&Qs[(wrow + i * 16 + l15) * 136 + kk + qd * 8];
#pragma unroll
            for (int j = 0; j < 4; j++)
                bfr[j] = *(const bf16x8*)&Ks[(j * 16 + l15) * 136 + kk + qd * 8];
#pragma unroll
            for (int i = 0; i < 2; i++)
#pragma unroll
                for (int j = 0; j < 4; j++)
                    sacc[i][j] = __builtin_amdgcn_mfma_f32_16x16x32_bf16(
                        af[i], bfr[j], sacc[i][j], 0, 0, 0);
        }

        // Online softmax update + P store (C-layout row = qd*4+r, col = lane&15)
#pragma unroll
        for (int i = 0; i < 2; i++) {
#pragma unroll
            for (int r = 0; r < 4; r++) {
                float s0 = sacc[i][0][r] * ATT_SCALE;
                float s1 = sacc[i][1][r] * ATT_SCALE;
                float s2 = sacc[i][2][r] * ATT_SCALE;
                float s3 = sacc[i][3][r] * ATT_SCALE;
                float mx = fmaxf(fmaxf(s0, s1), fmaxf(s2, s3));
#pragma unroll
                for (int off = 1; off < 16; off <<= 1)
                    mx = fmaxf(mx, __shfl_xor(mx, off));
                float mnew = fmaxf(m_s[i][r], mx);
                float alpha = __expf(m_s[i][r] - mnew);
                float p0 = __expf(s0 - mnew), p1 = __expf(s1 - mnew);
                float p2 = __expf(s2 - mnew), p3 = __expf(s3 - mnew);
                float rs = (p0 + p1) + (p2 + p3);
#pragma unroll
                for (int off = 1; off < 16; off <<= 1) rs += __shfl_xor(rs, off);
                l_s[i][r] = l_s[i][r] * alpha + rs;
                m_s[i][r] = mnew;
                int prow = (i * 16 + qd * 4 + r) * 72;
                Ps[w][prow + 0 + l15] = f2bf(p0);
                Ps[w][prow + 16 + l15] = f2bf(p1);
                Ps[w][prow + 32 + l15] = f2bf(p2);
                Ps[w][prow + 48 + l15] = f2bf(p3);
#pragma unroll
                for (int jo = 0; jo < 8; jo++) oacc[i][jo][r] *= alpha;
            }
        }
        __syncthreads();  // P stores drained before A-frag reads

        // O += P V
#pragma unroll
        for (int kk = 0; kk < 64; kk += 32) {
            bf16x8 pf[2], vf[8];
#pragma unroll
            for (int i = 0; i < 2; i++)
                pf[i] = *(const bf16x8*)&Ps[w][(i * 16 + l15) * 72 + kk + qd * 8];
#pragma unroll
            for (int jo = 0; jo < 8; jo++)
                vf[jo] = *(const bf16x8*)&Vts[(jo * 16 + l15) * 72 + kk + qd * 8];
#pragma unroll
            for (int i = 0; i < 2; i++)
#pragma unroll
                for (int jo = 0; jo < 8; jo++)
                    oacc[i][jo] = __builtin_amdgcn_mfma_f32_16x16x32_bf16(
                        pf[i], vf[jo], oacc[i][jo], 0, 0, 0);
        }
    }

    // Epilogue: O / l, write to (B, T, H*D) for the output GEMM.
#pragma unroll
    for (int i = 0; i < 2; i++) {
#pragma unroll
        for (int r = 0; r < 4; r++) {
            float inv = 1.0f / l_s[i][r];
            int tg = qt * 128 + wrow + i * 16 + qd * 4 + r;
            size_t base = ((size_t)b * 2048 + tg) * 4096 + h * 128;
#pragma unroll
            for (int jo = 0; jo < 8; jo++)
                Oo[base + jo * 16 + l15] = f2bf(oacc[i][jo][r] * inv);
        }
    }
}

// ---------------------------------------------------------------------------
extern "C" void kernel_launch(void* const* d_in, const int* in_sizes, int n_in,
                              void* d_out, int out_size, void* d_ws, size_t ws_size,
                              hipStream_t stream) {
    const float* hidden = (const float*)d_in[0];  // (2,2048,4096) fp32
    const float* Wqkv   = (const float*)d_in[1];  // (5120, 4096)  fp32
    const float* Wo     = (const float*)d_in[2];  // (4096, 4096)  fp32
    const float* qw     = (const float*)d_in[3];  // (32, 128)     fp32
    const float* kw     = (const float*)d_in[4];  // (4, 128)      fp32
    float* out = (float*)d_out;                   // (2,2048,4096) fp32

    // Workspace regions (lifetime-overlapped), total 117,440,512 B:
    char* ws = (char*)d_ws;
    bf16_t* Wqkv_bf = (bf16_t*)ws;                   // [cvt -> gemm1]
    bf16_t* q_r     = (bf16_t*)ws;                   // [rmsrope -> flash]
    bf16_t* k_r     = (bf16_t*)(ws + 33554432ull);
    bf16_t* v_r     = (bf16_t*)(ws + 37748736ull);
    bf16_t* qkv     = (bf16_t*)(ws + 41943040ull);   // [gemm1 -> rmsrope]
    bf16_t* attn    = (bf16_t*)(ws + 41943040ull);   // [flash -> gemm2]
    bf16_t* Wo_bf   = (bf16_t*)(ws + 83886080ull);   // [cvt -> gemm2]

    // 0) convert weights to bf16
    hipLaunchKernelGGL(cvt_f32_bf16, dim3(10240), dim3(256), 0, stream,
                       Wqkv, Wqkv_bf, 5120 * 4096 / 8);
    hipLaunchKernelGGL(cvt_f32_bf16, dim3(8192), dim3(256), 0, stream,
                       Wo, Wo_bf, 4096 * 4096 / 8);
    // 1) qkv = hidden @ Wqkv^T        M=4096 N=5120 K=4096 (A fp32 -> cvt in staging)
    hipLaunchKernelGGL((gemm_bt<float, bf16_t>), dim3(40, 32), dim3(256), 0, stream,
                       hidden, Wqkv_bf, qkv, 4096, 5120, 4096);
    // 2) norm + RoPE + reshape
    hipLaunchKernelGGL(rmsrope, dim3(40960), dim3(256), 0, stream,
                       qkv, qw, kw, q_r, k_r, v_r);
    // 3) attention
    hipLaunchKernelGGL(flash_attn, dim3(16, 64), dim3(256), 0, stream,
                       q_r, k_r, v_r, attn);
    // 4) out = attn @ Wo^T            M=4096 N=4096 K=4096 (out fp32)
    hipLaunchKernelGGL((gemm_bt<bf16_t, float>), dim3(32, 32), dim3(256), 0, stream,
                       attn, Wo_bf, out, 4096, 4096, 4096);
}

// Round 3
// 1007.212 us; speedup vs baseline: 1.1809x; 1.1809x over previous
//
#include <hip/hip_runtime.h>

typedef __bf16 bf16_t;
typedef __bf16 bf16x4 __attribute__((ext_vector_type(4)));
typedef __bf16 bf16x8 __attribute__((ext_vector_type(8)));
typedef float floatx4 __attribute__((ext_vector_type(4)));

__device__ __forceinline__ float bf2f(bf16_t x) { return (float)x; }
__device__ __forceinline__ bf16_t f2bf(float x) { return (bf16_t)x; }

// async 16B global -> LDS (global_load_lds_dwordx4). LDS dst must be
// wave-uniform base + lane*16 (m97 pattern; no padding in staged tiles).
__device__ __forceinline__ void async_copy16(const bf16_t* g, bf16_t* l) {
    __builtin_amdgcn_global_load_lds(
        (const __attribute__((address_space(1))) unsigned int*)g,
        (__attribute__((address_space(3))) unsigned int*)l, 16, 0, 0);
}

// ---------------------------------------------------------------------------
// fp32 -> bf16 elementwise convert (8 elems/thread, 16B stores). n8 = n/8.
// ---------------------------------------------------------------------------
__global__ __launch_bounds__(256) void cvt_f32_bf16(const float* __restrict__ in,
                                                    bf16_t* __restrict__ out,
                                                    int n8) {
    int i = blockIdx.x * blockDim.x + threadIdx.x;
    if (i >= n8) return;
    const float4* p = (const float4*)in + (size_t)i * 2;
    float4 a = p[0], b = p[1];
    bf16x8 v;
    v[0] = f2bf(a.x); v[1] = f2bf(a.y); v[2] = f2bf(a.z); v[3] = f2bf(a.w);
    v[4] = f2bf(b.x); v[5] = f2bf(b.y); v[6] = f2bf(b.z); v[7] = f2bf(b.w);
    *(bf16x8*)(out + (size_t)i * 8) = v;
}

// ---------------------------------------------------------------------------
// B^T GEMM, m97 structure: 128x128 tile, BK=32, 4 waves, 4x4 acc,
// global_load_lds width-16 staging (874 TF on this shape per ladder).
// C[m][n] = sum_k A[m*K+k] * B[n*K+k]; A,B bf16; C fp32 or bf16.
// ---------------------------------------------------------------------------
template <typename OT>
__global__ __launch_bounds__(256) void gemm_bt(const bf16_t* __restrict__ A,
                                               const bf16_t* __restrict__ B,
                                               OT* __restrict__ C,
                                               int M, int N, int K) {
    __shared__ __attribute__((aligned(16))) bf16_t As[128 * 32];
    __shared__ __attribute__((aligned(16))) bf16_t Bs[128 * 32];
    const int tid = threadIdx.x;
    const int lane = tid & 63;
    const int w = tid >> 6;
    const int l15 = lane & 15, qd = lane >> 4;
    const int tm = blockIdx.y * 128, tn = blockIdx.x * 128;
    const int wm = (w >> 1) * 64, wn = (w & 1) * 64;

    floatx4 acc[4][4] = {};

    for (int k0 = 0; k0 < K; k0 += 32) {
#pragma unroll
        for (int it = 0; it < 2; ++it) {
            int c = it * 256 + tid;          // 512 chunks of 16B per matrix
            int row = c >> 2, col = (c & 3) * 8;
            // LDS offset c*16B == (row*32+col)*2B; within a wave this is
            // wave-uniform base + lane*16 -> legal for global_load_lds.
            async_copy16(&A[(size_t)(tm + row) * K + k0 + col], &As[c * 8]);
            async_copy16(&B[(size_t)(tn + row) * K + k0 + col], &Bs[c * 8]);
        }
        __syncthreads();   // compiler emits vmcnt(0) drain before s_barrier
        bf16x8 af[4], bfr[4];
#pragma unroll
        for (int i = 0; i < 4; i++)
            af[i] = *(const bf16x8*)&As[(wm + i * 16 + l15) * 32 + qd * 8];
#pragma unroll
        for (int j = 0; j < 4; j++)
            bfr[j] = *(const bf16x8*)&Bs[(wn + j * 16 + l15) * 32 + qd * 8];
#pragma unroll
        for (int i = 0; i < 4; i++)
#pragma unroll
            for (int j = 0; j < 4; j++)
                acc[i][j] = __builtin_amdgcn_mfma_f32_16x16x32_bf16(
                    af[i], bfr[j], acc[i][j], 0, 0, 0);
        __syncthreads();
    }
    // C/D layout: col = lane&15, row = quad*4 + reg  (m89/m91 verified)
#pragma unroll
    for (int i = 0; i < 4; i++) {
        int row = tm + wm + i * 16 + qd * 4;
#pragma unroll
        for (int j = 0; j < 4; j++) {
            int col = tn + wn + j * 16 + l15;
#pragma unroll
            for (int r = 0; r < 4; r++)
                C[(size_t)(row + r) * N + col] = (OT)acc[i][j][r];
        }
    }
}

// ---------------------------------------------------------------------------
// Reference-faithful "norm" + RoPE + layout transform.
// Reference: q = rsqrt(mean(q*q)+eps) * q_weight  (NO multiply by q).
// ---------------------------------------------------------------------------
__global__ __launch_bounds__(256) void rmsrope(const bf16_t* __restrict__ qkv,
                                               const float* __restrict__ qw,
                                               const float* __restrict__ kw,
                                               bf16_t* __restrict__ q_r,
                                               bf16_t* __restrict__ k_r,
                                               bf16_t* __restrict__ v_r) {
    const int tid = threadIdx.x, lane = tid & 63, w = tid >> 6;
    const int slot = blockIdx.x * 4 + w;       // [0, 163840)
    const int row = slot / 40;
    const int hs = slot - row * 40;
    const int b = row >> 11, t = row & 2047;
    const bf16_t* src = qkv + (size_t)row * 5120 + hs * 128;

    if (hs >= 36) {  // v: passthrough reshape
        size_t dst = ((size_t)((b * 4 + (hs - 36)) * 2048 + t)) * 128;
        v_r[dst + lane] = src[lane];
        v_r[dst + lane + 64] = src[lane + 64];
        return;
    }
    float x1 = bf2f(src[lane]);
    float x2 = bf2f(src[lane + 64]);
    float ss = x1 * x1 + x2 * x2;
#pragma unroll
    for (int off = 1; off < 64; off <<= 1) ss += __shfl_xor(ss, off);
    const float rr = rsqrtf(ss * (1.0f / 128.0f) + 1e-6f);

    const float* wp;
    bf16_t* dstp;
    if (hs < 32) {
        wp = qw + hs * 128;
        dstp = q_r + ((size_t)((b * 32 + hs) * 2048 + t)) * 128;
    } else {
        wp = kw + (hs - 32) * 128;
        dstp = k_r + ((size_t)((b * 4 + (hs - 32)) * 2048 + t)) * 128;
    }
    float n1 = rr * wp[lane];
    float n2 = rr * wp[lane + 64];
    float inv_freq = exp2f((float)lane * -0.20762050593046f);
    float th = (float)t * inv_freq;
    float sn, cs;
    sincosf(th, &sn, &cs);
    dstp[lane] = f2bf(n1 * cs - n2 * sn);
    dstp[lane + 64] = f2bf(n1 * sn + n2 * cs);
}

// ---------------------------------------------------------------------------
// Flash attention v2: Q fragments in registers (no Qs), LDS 54.3 KB ->
// 2 blocks/CU.  P and V share a k-permutation pi(k)=(k&15)*4+(k>>4) so the
// P store is one ds_write_b64 per row (was 4 scalar b16).  2 barriers/iter.
// ---------------------------------------------------------------------------
#define ATT_SCALE 0.08838834764831845f

__global__ __launch_bounds__(256, 2) void flash_attn(const bf16_t* __restrict__ Qr,
                                                     const bf16_t* __restrict__ Kr,
                                                     const bf16_t* __restrict__ Vr,
                                                     bf16_t* __restrict__ Oo) {
    __shared__ __attribute__((aligned(16))) bf16_t Ks[64 * 136];
    __shared__ __attribute__((aligned(16))) bf16_t Vts[128 * 72];  // Vts[d][pi(k)]
    __shared__ __attribute__((aligned(16))) bf16_t Ps[4][32 * 72]; // Ps[q][pi(k)]
    const int tid = threadIdx.x, lane = tid & 63, w = tid >> 6;
    const int l15 = lane & 15, qd = lane >> 4;
    const int qt = blockIdx.x, bh = blockIdx.y;
    const int b = bh >> 5, h = bh & 31;
    const int kvh = h >> 3;  // GROUP = 8
    const bf16_t* Qb = Qr + ((size_t)(b * 32 + h) * 2048 + qt * 128) * 128;
    const bf16_t* Kb = Kr + ((size_t)(b * 4 + kvh) * 2048) * 128;
    const bf16_t* Vb = Vr + ((size_t)(b * 4 + kvh) * 2048) * 128;
    const int wrow = w * 32;
    const int pi = l15 * 4 + qd;            // pi(lane) for V transpose writes

    // Q fragments in registers: A[m=l15][k=qd*8+j], 32 rows x 128 k per wave.
    bf16x8 qf[2][4];
#pragma unroll
    for (int i = 0; i < 2; i++)
#pragma unroll
        for (int kk = 0; kk < 4; kk++)
            qf[i][kk] = *(const bf16x8*)&Qb[(size_t)(wrow + i * 16 + l15) * 128 +
                                            kk * 32 + qd * 8];

    float m_s[2][4], l_s[2][4];
    floatx4 oacc[2][8] = {};
#pragma unroll
    for (int i = 0; i < 2; i++)
#pragma unroll
        for (int r = 0; r < 4; r++) { m_s[i][r] = -1e30f; l_s[i][r] = 0.0f; }

    for (int kt = 0; kt < 32; ++kt) {
        __syncthreads();  // prev iteration's reads of Ks/Vts done
        // stage K tile (64 x 128) -> Ks (padded rows, VGPR path)
#pragma unroll
        for (int it = 0; it < 4; ++it) {
            int c = it * 256 + tid;
            int row = c >> 4, col = (c & 15) * 8;
            *(bf16x8*)&Ks[row * 136 + col] =
                *(const bf16x8*)&Kb[(size_t)(kt * 64 + row) * 128 + col];
        }
        // stage V transposed with pi: Vts[d][pi(k)] = V[k][d]
#pragma unroll
        for (int it = 0; it < 4; ++it) {
            int d0 = (it * 4 + w) * 8;
            bf16x8 v = *(const bf16x8*)&Vb[(size_t)(kt * 64 + lane) * 128 + d0];
#pragma unroll
            for (int e = 0; e < 8; ++e) Vts[(d0 + e) * 72 + pi] = v[e];
        }
        __syncthreads();

        // S = Q K^T for this wave's 32 rows x 64 keys
        floatx4 sacc[2][4] = {};
#pragma unroll
        for (int kk = 0; kk < 4; kk++) {
            bf16x8 bfr[4];
#pragma unroll
            for (int j = 0; j < 4; j++)
                bfr[j] = *(const bf16x8*)&Ks[(j * 16 + l15) * 136 + kk * 32 + qd * 8];
#pragma unroll
            for (int i = 0; i < 2; i++)
#pragma unroll
                for (int j = 0; j < 4; j++)
                    sacc[i][j] = __builtin_amdgcn_mfma_f32_16x16x32_bf16(
                        qf[i][kk], bfr[j], sacc[i][j], 0, 0, 0);
        }

        // Online softmax + P store.  p_j has k = j*16+l15 -> pi = l15*4+j, so
        // {p0..p3} are contiguous: one 8B vector store per row.
#pragma unroll
        for (int i = 0; i < 2; i++) {
#pragma unroll
            for (int r = 0; r < 4; r++) {
                float s0 = sacc[i][0][r] * ATT_SCALE;
                float s1 = sacc[i][1][r] * ATT_SCALE;
                float s2 = sacc[i][2][r] * ATT_SCALE;
                float s3 = sacc[i][3][r] * ATT_SCALE;
                float mx = fmaxf(fmaxf(s0, s1), fmaxf(s2, s3));
#pragma unroll
                for (int off = 1; off < 16; off <<= 1)
                    mx = fmaxf(mx, __shfl_xor(mx, off));
                float mnew = fmaxf(m_s[i][r], mx);
                float alpha = __expf(m_s[i][r] - mnew);
                float p0 = __expf(s0 - mnew), p1 = __expf(s1 - mnew);
                float p2 = __expf(s2 - mnew), p3 = __expf(s3 - mnew);
                float rs = (p0 + p1) + (p2 + p3);
#pragma unroll
                for (int off = 1; off < 16; off <<= 1) rs += __shfl_xor(rs, off);
                l_s[i][r] = l_s[i][r] * alpha + rs;
                m_s[i][r] = mnew;
                bf16x4 pv;
                pv[0] = f2bf(p0); pv[1] = f2bf(p1);
                pv[2] = f2bf(p2); pv[3] = f2bf(p3);
                *(bf16x4*)&Ps[w][(i * 16 + qd * 4 + r) * 72 + l15 * 4] = pv;
#pragma unroll
                for (int jo = 0; jo < 8; jo++) oacc[i][jo][r] *= alpha;
            }
        }
        // No barrier: Ps[w] is wave-private; same-wave DS ops are ordered.

        // O += P V  (both operands in pi-order along k; sum over k unaffected)
#pragma unroll
        for (int kk = 0; kk < 64; kk += 32) {
            bf16x8 pf[2], vf[8];
#pragma unroll
            for (int i = 0; i < 2; i++)
                pf[i] = *(const bf16x8*)&Ps[w][(i * 16 + l15) * 72 + kk + qd * 8];
#pragma unroll
            for (int jo = 0; jo < 8; jo++)
                vf[jo] = *(const bf16x8*)&Vts[(jo * 16 + l15) * 72 + kk + qd * 8];
#pragma unroll
            for (int i = 0; i < 2; i++)
#pragma unroll
                for (int jo = 0; jo < 8; jo++)
                    oacc[i][jo] = __builtin_amdgcn_mfma_f32_16x16x32_bf16(
                        pf[i], vf[jo], oacc[i][jo], 0, 0, 0);
        }
    }

    // Epilogue: O / l, write to (B, T, H*D) for the output GEMM.
#pragma unroll
    for (int i = 0; i < 2; i++) {
#pragma unroll
        for (int r = 0; r < 4; r++) {
            float inv = 1.0f / l_s[i][r];
            int tg = qt * 128 + wrow + i * 16 + qd * 4 + r;
            size_t base = ((size_t)b * 2048 + tg) * 4096 + h * 128;
#pragma unroll
            for (int jo = 0; jo < 8; jo++)
                Oo[base + jo * 16 + l15] = f2bf(oacc[i][jo][r] * inv);
        }
    }
}

// ---------------------------------------------------------------------------
extern "C" void kernel_launch(void* const* d_in, const int* in_sizes, int n_in,
                              void* d_out, int out_size, void* d_ws, size_t ws_size,
                              hipStream_t stream) {
    const float* hidden = (const float*)d_in[0];  // (2,2048,4096) fp32
    const float* Wqkv   = (const float*)d_in[1];  // (5120, 4096)  fp32
    const float* Wo     = (const float*)d_in[2];  // (4096, 4096)  fp32
    const float* qw     = (const float*)d_in[3];  // (32, 128)     fp32
    const float* kw     = (const float*)d_in[4];  // (4, 128)      fp32
    float* out = (float*)d_out;                   // (2,2048,4096) fp32

    // Region plan (peak = 117,440,512 B, same footprint round 2 proved):
    //   R0 [0, 41.9M):    Wqkv_bf (cvt->gemm1)  then  q_r/k_r/v_r (rms->flash)
    //   R1 [41.9M, 75.5M): hidden_bf (cvt->gemm1) then attn (flash->gemm2)
    //   R2 [75.5M, 117.4M): qkv (gemm1->rms)     then  Wo_bf (cvt->gemm2)
    char* ws = (char*)d_ws;
    bf16_t* Wqkv_bf   = (bf16_t*)ws;
    bf16_t* q_r       = (bf16_t*)ws;
    bf16_t* k_r       = (bf16_t*)(ws + 33554432ull);
    bf16_t* v_r       = (bf16_t*)(ws + 37748736ull);
    bf16_t* hidden_bf = (bf16_t*)(ws + 41943040ull);
    bf16_t* attn      = (bf16_t*)(ws + 41943040ull);
    bf16_t* qkv       = (bf16_t*)(ws + 75497472ull);
    bf16_t* Wo_bf     = (bf16_t*)(ws + 75497472ull);

    hipLaunchKernelGGL(cvt_f32_bf16, dim3(8192), dim3(256), 0, stream,
                       hidden, hidden_bf, 16777216 / 8);
    hipLaunchKernelGGL(cvt_f32_bf16, dim3(10240), dim3(256), 0, stream,
                       Wqkv, Wqkv_bf, 20971520 / 8);
    // 1) qkv = hidden @ Wqkv^T   M=4096 N=5120 K=4096
    hipLaunchKernelGGL((gemm_bt<bf16_t>), dim3(40, 32), dim3(256), 0, stream,
                       hidden_bf, Wqkv_bf, qkv, 4096, 5120, 4096);
    // 2) norm + RoPE + reshape (frees qkv afterwards)
    hipLaunchKernelGGL(rmsrope, dim3(40960), dim3(256), 0, stream,
                       qkv, qw, kw, q_r, k_r, v_r);
    // 3) convert Wo into qkv's region (now dead)
    hipLaunchKernelGGL(cvt_f32_bf16, dim3(8192), dim3(256), 0, stream,
                       Wo, Wo_bf, 16777216 / 8);
    // 4) attention
    hipLaunchKernelGGL(flash_attn, dim3(16, 64), dim3(256), 0, stream,
                       q_r, k_r, v_r, attn);
    // 5) out = attn @ Wo^T   M=4096 N=4096 K=4096 (fp32 out)
    hipLaunchKernelGGL((gemm_bt<float>), dim3(32, 32), dim3(256), 0, stream,
                       attn, Wo_bf, out, 4096, 4096, 4096);
}